// Round 12
// baseline (562.861 us; speedup 1.0000x reference)
//
#include <hip/hip_runtime.h>

#define NN 30000
#define NE 300000
#define D_IN 256
#define D_H 128
#define D_OUT 64
#define NL 6
#define NB ((NN + 255) / 256)
#define NTILE (NN / 16)          // 1875, exact
#define G0TILE ((NN + 31) / 32)  // 938

typedef unsigned short ushort_t;
typedef unsigned int uint_t;
typedef __attribute__((ext_vector_type(8))) short sh8;
typedef __attribute__((ext_vector_type(4))) float f4;

// fp32 -> bf16 round-to-nearest-even
static __device__ __forceinline__ ushort_t f2bf(float f) {
    uint_t u = __float_as_uint(f);
    u = (u + 0x7FFFu + ((u >> 16) & 1u)) >> 16;
    return (ushort_t)u;
}

// ---------------------------------------------------------------------------
// Setup kernels
// ---------------------------------------------------------------------------
__global__ void degree_kernel(const int* __restrict__ src, const int* __restrict__ dst,
                              int* __restrict__ outdeg, int* __restrict__ indeg) {
    int e = blockIdx.x * blockDim.x + threadIdx.x;
    if (e < NE) {
        atomicAdd(&outdeg[src[e]], 1);
        atomicAdd(&indeg[dst[e]], 1);
    }
}

__global__ void rsqrt_kernel(const int* __restrict__ deg, float* __restrict__ inv, int n) {
    int i = blockIdx.x * blockDim.x + threadIdx.x;
    if (i < n) {
        float d = (float)deg[i];
        inv[i] = rsqrtf(d < 1.0f ? 1.0f : d);
    }
}

__global__ __launch_bounds__(256) void bsum_kernel(const int* __restrict__ deg,
                                                   int* __restrict__ bsum) {
    __shared__ int wsum[4];
    int t = threadIdx.x, lane = t & 63, w = t >> 6;
    int i = blockIdx.x * 256 + t;
    int v = (i < NN) ? deg[i] : 0;
#pragma unroll
    for (int off = 32; off; off >>= 1) v += __shfl_down(v, off, 64);
    if (lane == 0) wsum[w] = v;
    __syncthreads();
    if (t == 0) bsum[blockIdx.x] = wsum[0] + wsum[1] + wsum[2] + wsum[3];
}

__global__ __launch_bounds__(128) void boffs_kernel(const int* __restrict__ bsum,
                                                    int* __restrict__ boffs,
                                                    int* __restrict__ row_ptr) {
    __shared__ int wtot[2];
    int t = threadIdx.x, lane = t & 63, w = t >> 6;
    int v = (t < NB) ? bsum[t] : 0;
    int s = v;
#pragma unroll
    for (int off = 1; off < 64; off <<= 1) {
        int x = __shfl_up(s, off, 64);
        if (lane >= off) s += x;
    }
    if (lane == 63) wtot[w] = s;
    __syncthreads();
    int add = (w == 1) ? wtot[0] : 0;
    if (t < NB) boffs[t] = add + s - v;
    if (t == 0) row_ptr[NN] = NE;
}

__global__ __launch_bounds__(256) void rowptr_kernel(const int* __restrict__ deg,
                                                     const int* __restrict__ boffs,
                                                     int* __restrict__ row_ptr) {
    __shared__ int wsum[4];
    int t = threadIdx.x, lane = t & 63, w = t >> 6;
    int i = blockIdx.x * 256 + t;
    int v = (i < NN) ? deg[i] : 0;
    int s = v;
#pragma unroll
    for (int off = 1; off < 64; off <<= 1) {
        int x = __shfl_up(s, off, 64);
        if (lane >= off) s += x;
    }
    if (lane == 63) wsum[w] = s;
    __syncthreads();
    int woff = 0;
#pragma unroll
    for (int k = 0; k < 4; k++)
        if (k < w) woff += wsum[k];
    if (i < NN) row_ptr[i] = boffs[blockIdx.x] + woff + s - v;
}

__global__ void fill_kernel(const int* __restrict__ src, const int* __restrict__ dst,
                            const int* __restrict__ row_ptr, int* __restrict__ cursor,
                            int* __restrict__ col) {
    int e = blockIdx.x * blockDim.x + threadIdx.x;
    if (e < NE) {
        int d = dst[e];
        int pos = atomicAdd(&cursor[d], 1);
        col[row_ptr[d] + pos] = src[e];
    }
}

// ---------------------------------------------------------------------------
// R12 (= R11 resubmit): degree-balanced permutation via counting sort on
// in-degree. Each fused block then owns 16 rows of near-equal degree -> the
// wave's edge loop (bounded by max over its 16 lanes' rows) wastes ~1.0x
// instead of ~1.75x (max of 16 Poisson(10) samples vs mean).
// ---------------------------------------------------------------------------
__global__ void hist_kernel(const int* __restrict__ indeg, int* __restrict__ hist) {
    int i = blockIdx.x * blockDim.x + threadIdx.x;
    if (i < NN) {
        int b = indeg[i]; if (b > 63) b = 63;
        atomicAdd(&hist[b], 1);
    }
}

__global__ __launch_bounds__(64) void hscan_kernel(const int* __restrict__ hist,
                                                   int* __restrict__ hoff) {
    int lane = threadIdx.x;          // 64 threads = 1 wave, 64 buckets
    int v = hist[lane];
    int s = v;
#pragma unroll
    for (int off = 1; off < 64; off <<= 1) {
        int t = __shfl_up(s, off, 64);
        if (lane >= off) s += t;
    }
    hoff[lane] = s - v;              // exclusive offsets (consumed as cursors)
}

__global__ void permscatter_kernel(const int* __restrict__ indeg,
                                   int* __restrict__ hoff,
                                   int* __restrict__ perm) {
    int i = blockIdx.x * blockDim.x + threadIdx.x;
    if (i < NN) {
        int b = indeg[i]; if (b > 63) b = 63;
        int pos = atomicAdd(&hoff[b], 1);
        perm[pos] = i;
    }
}

__global__ void packw_kernel(const float* __restrict__ W0,
                             const float* __restrict__ Wh,
                             const float* __restrict__ Wout,
                             ushort_t* __restrict__ W0p,
                             ushort_t* __restrict__ Whp,
                             ushort_t* __restrict__ Woutp) {
    int g = blockIdx.x * blockDim.x + threadIdx.x;
    int frag = g >> 6;
    int lane = g & 63;
    if (frag >= 368) return;
    const float* srcw;
    ushort_t* dstp;
    int fl, KF, M;
    if (frag < 64) {                     // W0
        fl = frag; KF = 8; M = 128;
        srcw = W0;
        dstp = W0p;
    } else if (frag < 64 + 192) {        // Wh
        int f2 = frag - 64;
        int l = f2 / 32; fl = f2 % 32; KF = 4; M = 128;
        srcw = Wh + (size_t)l * D_H * D_H;
        dstp = Whp + (size_t)l * 32 * 512;
    } else {                             // Wout blocks
        int f2 = frag - 256;
        int l = f2 / 16; fl = f2 % 16; KF = 4; M = 64;
        srcw = Wout + (size_t)l * D_H * D_OUT;
        dstp = Woutp + (size_t)l * 16 * 512;
    }
    int ct = fl / KF;
    int kt = fl % KF;
    int krow = kt * 32 + (lane >> 4) * 8;
    int cidx = ct * 16 + (lane & 15);
    ushort_t tmp[8];
#pragma unroll
    for (int j = 0; j < 8; j++)
        tmp[j] = f2bf(srcw[(size_t)(krow + j) * M + cidx]);
    uint4 o;
    o.x = (uint_t)tmp[0] | ((uint_t)tmp[1] << 16);
    o.y = (uint_t)tmp[2] | ((uint_t)tmp[3] << 16);
    o.z = (uint_t)tmp[4] | ((uint_t)tmp[5] << 16);
    o.w = (uint_t)tmp[6] | ((uint_t)tmp[7] << 16);
    *(uint4*)(dstp + (size_t)fl * 512 + lane * 8) = o;
}

// ---------------------------------------------------------------------------
// Layer-0 GEMM: reads feats fp32 directly, converts to bf16 A-fragments
// in-register. Tb[row,:] = bf16( (feats[row,:] @ W0) * inv_out[row] )
// (dense, no divergence -> no perm needed here)
// ---------------------------------------------------------------------------
__global__ __launch_bounds__(256) void gemm0_kernel(
    const float* __restrict__ X,
    const ushort_t* __restrict__ W1p,
    const float* __restrict__ scale,
    ushort_t* __restrict__ Tb)
{
    constexpr int KF = 8;
    const int lane = threadIdx.x & 63;
    const int w = threadIdx.x >> 6;
    const int rg = w >> 1;
    const int cgrp = w & 1;
    const int row0 = blockIdx.x * 32 + rg * 16;

    int arow = row0 + (lane & 15);
    if (arow >= NN) arow = NN - 1;
    const float* xr = X + (size_t)arow * D_IN + ((lane >> 4) * 8);
    sh8 a[KF];
#pragma unroll
    for (int kt = 0; kt < KF; kt++) {
        float4 lo = *(const float4*)(xr + kt * 32);
        float4 hi = *(const float4*)(xr + kt * 32 + 4);
        sh8 t;
        t[0] = (short)f2bf(lo.x); t[1] = (short)f2bf(lo.y);
        t[2] = (short)f2bf(lo.z); t[3] = (short)f2bf(lo.w);
        t[4] = (short)f2bf(hi.x); t[5] = (short)f2bf(hi.y);
        t[6] = (short)f2bf(hi.z); t[7] = (short)f2bf(hi.w);
        a[kt] = t;
    }

    const int crow0 = row0 + (lane >> 4) * 4;
    float s[4];
#pragma unroll
    for (int r = 0; r < 4; r++) {
        int rw = crow0 + r;
        s[r] = scale[rw < NN ? rw : NN - 1];
    }
#pragma unroll
    for (int i = 0; i < 4; i++) {
        int ct = cgrp * 4 + i;
        f4 acc = {0.f, 0.f, 0.f, 0.f};
        const ushort_t* wp = W1p + ((size_t)(ct * KF) << 9) + lane * 8;
#pragma unroll
        for (int kt = 0; kt < KF; kt++)
            acc = __builtin_amdgcn_mfma_f32_16x16x32_bf16(
                a[kt], *(const sh8*)(wp + ((size_t)kt << 9)), acc, 0, 0, 0);
        int colb = ct * 16 + (lane & 15);
#pragma unroll
        for (int r = 0; r < 4; r++) {
            int rw = crow0 + r;
            if (rw < NN)
                Tb[(size_t)rw * 128 + colb] = f2bf(acc[r] * s[r]);
        }
    }
}

// ---------------------------------------------------------------------------
// Fused gather + GEMM, 4 waves per block, 16 degree-matched rows per block
// (rows perm[b*16 .. b*16+16)). Each wave gathers a contiguous quarter of
// each row's edge list; LDS combine; 12 MFMA ct-units (8 T + 4 P), 3/wave.
// perm is bijective -> each block writes 16 distinct T/P rows; T reads stay
// node-indexed; scales/bias indexed by true node id.
// ---------------------------------------------------------------------------
static __device__ __forceinline__ void acc8(float* acc, uint4 u) {
    uint_t wv[4] = {u.x, u.y, u.z, u.w};
#pragma unroll
    for (int i = 0; i < 4; i++) {
        acc[2 * i]     += __uint_as_float(wv[i] << 16);
        acc[2 * i + 1] += __uint_as_float(wv[i] & 0xFFFF0000u);
    }
}

template <bool HAS_T, bool HAS_P>
__global__ __launch_bounds__(256, 5) void fused4_kernel(
    const ushort_t* __restrict__ Tin,
    const int* __restrict__ row_ptr,
    const int* __restrict__ col,
    const int* __restrict__ perm,
    const float* __restrict__ inv_in,
    const float* __restrict__ bias,      // [128] fp32
    const ushort_t* __restrict__ W1p,    // Wh packed (KF=4), may be null
    const ushort_t* __restrict__ W2p,    // Wout block packed (KF=4)
    const float* __restrict__ inv_out,   // may be null
    ushort_t* __restrict__ Tout,         // may be null
    float* __restrict__ P)
{
    __shared__ float part[4 * 32 * 64];  // [wave][feat(kt*8+i)][lane], 32 KB
    const int tid = threadIdx.x;
    const int lane = tid & 63;
    const int w = tid >> 6;
    const int row0 = blockIdx.x * 16;    // NN % 16 == 0
    const int r = perm[row0 + (lane & 15)];   // degree-matched true node id
    const int beg = row_ptr[r];
    const int end = row_ptr[r + 1];
    const int cb = (lane >> 4) * 8;      // col base (bf16 units)
    const int cq = (lane >> 4) * 4;      // col base (uint units)

    // this wave's contiguous quarter of the row's edge list
    const int cnt = end - beg;
    const int j0 = beg + ((cnt * w) >> 2);
    const int j1 = beg + ((cnt * (w + 1)) >> 2);

    float acc[4][8];
#pragma unroll
    for (int kt = 0; kt < 4; kt++)
#pragma unroll
        for (int i = 0; i < 8; i++) acc[kt][i] = 0.f;

    const uint_t* T32 = (const uint_t*)Tin;   // row = 64 uints
    int j = j0;
    for (; j + 1 < j1; j += 2) {
        int c0 = col[j], c1 = col[j + 1];
        const uint_t* p0 = T32 + (size_t)c0 * 64 + cq;
        const uint_t* p1 = T32 + (size_t)c1 * 64 + cq;
        uint4 u00 = *(const uint4*)(p0);
        uint4 u01 = *(const uint4*)(p0 + 16);
        uint4 u02 = *(const uint4*)(p0 + 32);
        uint4 u03 = *(const uint4*)(p0 + 48);
        uint4 u10 = *(const uint4*)(p1);
        uint4 u11 = *(const uint4*)(p1 + 16);
        uint4 u12 = *(const uint4*)(p1 + 32);
        uint4 u13 = *(const uint4*)(p1 + 48);
        acc8(acc[0], u00); acc8(acc[0], u10);
        acc8(acc[1], u01); acc8(acc[1], u11);
        acc8(acc[2], u02); acc8(acc[2], u12);
        acc8(acc[3], u03); acc8(acc[3], u13);
    }
    if (j < j1) {
        int c0 = col[j];
        const uint_t* p0 = T32 + (size_t)c0 * 64 + cq;
        acc8(acc[0], *(const uint4*)(p0));
        acc8(acc[1], *(const uint4*)(p0 + 16));
        acc8(acc[2], *(const uint4*)(p0 + 32));
        acc8(acc[3], *(const uint4*)(p0 + 48));
    }

    // publish partials: [w][kt*8+i][lane] -> bank = lane%32, conflict-free
#pragma unroll
    for (int kt = 0; kt < 4; kt++)
#pragma unroll
        for (int i = 0; i < 8; i++)
            part[(w * 32 + kt * 8 + i) * 64 + lane] = acc[kt][i];
    __syncthreads();

    // each wave completes the sum for its own lane slot (adds 3 other waves)
#pragma unroll
    for (int ow = 1; ow < 4; ow++) {
        int w2 = (w + ow) & 3;
#pragma unroll
        for (int kt = 0; kt < 4; kt++)
#pragma unroll
            for (int i = 0; i < 8; i++)
                acc[kt][i] += part[(w2 * 32 + kt * 8 + i) * 64 + lane];
    }

    // finish: bias + relu + inv_in scale, convert to A-fragments
    const float s = inv_in[r];
    sh8 a[4];
#pragma unroll
    for (int kt = 0; kt < 4; kt++) {
        float4 b0 = *(const float4*)(bias + kt * 32 + cb);
        float4 b1 = *(const float4*)(bias + kt * 32 + cb + 4);
        float bb[8] = {b0.x, b0.y, b0.z, b0.w, b1.x, b1.y, b1.z, b1.w};
        sh8 t;
#pragma unroll
        for (int i = 0; i < 8; i++) {
            float h = fmaxf(fmaf(acc[kt][i], s, bb[i]), 0.f);
            t[i] = (short)f2bf(h);
        }
        a[kt] = t;
    }

    // output rows for the MFMA C-tile (perm'd true node ids)
    const int crow0 = row0 + (lane >> 4) * 4;
    int prow[4];
#pragma unroll
    for (int rr = 0; rr < 4; rr++)
        prow[rr] = perm[crow0 + rr];

    if (HAS_T) {
        // 12 units (T ct 0..7, P ct 0..3), 3 per wave
        float sc[4];
#pragma unroll
        for (int rr = 0; rr < 4; rr++)
            sc[rr] = inv_out[prow[rr]];
#pragma unroll
        for (int u = 0; u < 3; u++) {
            int unit = w * 3 + u;
            if (unit < 8) {
                int ct = unit;
                f4 accT = {0.f, 0.f, 0.f, 0.f};
                const ushort_t* wp = W1p + ((size_t)(ct * 4) << 9) + lane * 8;
#pragma unroll
                for (int kt = 0; kt < 4; kt++)
                    accT = __builtin_amdgcn_mfma_f32_16x16x32_bf16(
                        a[kt], *(const sh8*)(wp + ((size_t)kt << 9)), accT, 0, 0, 0);
                int colb = ct * 16 + (lane & 15);
#pragma unroll
                for (int rr = 0; rr < 4; rr++)
                    Tout[(size_t)prow[rr] * 128 + colb] = f2bf(accT[rr] * sc[rr]);
            } else {
                int ct = unit - 8;
                f4 accP = {0.f, 0.f, 0.f, 0.f};
                const ushort_t* wp = W2p + ((size_t)(ct * 4) << 9) + lane * 8;
#pragma unroll
                for (int kt = 0; kt < 4; kt++)
                    accP = __builtin_amdgcn_mfma_f32_16x16x32_bf16(
                        a[kt], *(const sh8*)(wp + ((size_t)kt << 9)), accP, 0, 0, 0);
                int colb = ct * 16 + (lane & 15);
#pragma unroll
                for (int rr = 0; rr < 4; rr++)
                    P[(size_t)prow[rr] * 64 + colb] += accP[rr];
            }
        }
    } else if (HAS_P) {
        // tail: 4 P units, 1 per wave
        int ct = w;
        f4 accP = {0.f, 0.f, 0.f, 0.f};
        const ushort_t* wp = W2p + ((size_t)(ct * 4) << 9) + lane * 8;
#pragma unroll
        for (int kt = 0; kt < 4; kt++)
            accP = __builtin_amdgcn_mfma_f32_16x16x32_bf16(
                a[kt], *(const sh8*)(wp + ((size_t)kt << 9)), accP, 0, 0, 0);
        int colb = ct * 16 + (lane & 15);
#pragma unroll
        for (int rr = 0; rr < 4; rr++)
            P[(size_t)prow[rr] * 64 + colb] += accP[rr];
    }
}

// fp32 final gather, degree-balanced: out[perm[slot],:] = sum p[col[j],:] + bout
__global__ __launch_bounds__(256) void gather_f32_kernel(
    const float* __restrict__ P,
    const int* __restrict__ row_ptr,
    const int* __restrict__ col,
    const int* __restrict__ perm,
    const float* __restrict__ bias,
    float* __restrict__ Y) {
    int idx = blockIdx.x * blockDim.x + threadIdx.x;
    int slot = idx >> 4;
    int q = idx & 15;
    if (slot >= NN) return;
    int node = perm[slot];
    int beg = row_ptr[node];
    int end = row_ptr[node + 1];
    float4 acc = make_float4(0.f, 0.f, 0.f, 0.f);
    int j = beg;
    for (; j + 3 < end; j += 4) {
        int c0 = col[j], c1 = col[j + 1], c2 = col[j + 2], c3 = col[j + 3];
        float4 v0 = *(const float4*)(P + (size_t)c0 * 64 + q * 4);
        float4 v1 = *(const float4*)(P + (size_t)c1 * 64 + q * 4);
        float4 v2 = *(const float4*)(P + (size_t)c2 * 64 + q * 4);
        float4 v3 = *(const float4*)(P + (size_t)c3 * 64 + q * 4);
        acc.x += (v0.x + v1.x) + (v2.x + v3.x);
        acc.y += (v0.y + v1.y) + (v2.y + v3.y);
        acc.z += (v0.z + v1.z) + (v2.z + v3.z);
        acc.w += (v0.w + v1.w) + (v2.w + v3.w);
    }
    for (; j < end; j++) {
        int c0 = col[j];
        float4 v0 = *(const float4*)(P + (size_t)c0 * 64 + q * 4);
        acc.x += v0.x; acc.y += v0.y; acc.z += v0.z; acc.w += v0.w;
    }
    float4 b = *(const float4*)(bias + q * 4);
    acc.x += b.x; acc.y += b.y; acc.z += b.z; acc.w += b.w;
    *(float4*)(Y + (size_t)node * 64 + q * 4) = acc;
}

// ---------------------------------------------------------------------------
extern "C" void kernel_launch(void* const* d_in, const int* in_sizes, int n_in,
                              void* d_out, int out_size, void* d_ws, size_t ws_size,
                              hipStream_t stream) {
    const float* feats = (const float*)d_in[0];
    const int*   src   = (const int*)d_in[1];
    const int*   dst   = (const int*)d_in[2];
    const float* W0    = (const float*)d_in[3];
    const float* b0    = (const float*)d_in[4];
    const float* Wh    = (const float*)d_in[5];
    const float* bh    = (const float*)d_in[6];
    const float* Wout  = (const float*)d_in[7];
    const float* bout  = (const float*)d_in[8];
    float* out = (float*)d_out;

    float* ws      = (float*)d_ws;
    float* inv_out = ws;                              // NN
    float* inv_in  = ws + NN;                         // NN
    float* p       = ws + 2 * NN;                     // NN*64 fp32
    ushort_t* tb   = (ushort_t*)(p + (size_t)NN * 64);      // NN*128 bf16
    ushort_t* ha   = tb + (size_t)NN * 128;           // NN*128 bf16
    ushort_t* hb   = ha + (size_t)NN * 128;           // NN*128 bf16 (scan scratch)
    ushort_t* fb   = hb + (size_t)NN * 128;           // NN*256 bf16 (unused)
    ushort_t* w0p  = fb + (size_t)NN * 256;           // 64*512
    ushort_t* whp  = w0p + 64 * 512;                  // 192*512
    ushort_t* wop  = whp + 192 * 512;                 // 112*512
    int* ibase     = (int*)(wop + 112 * 512);
    int* outdeg_i  = ibase;                           // NN, zeroed
    int* indeg_i   = ibase + NN;                      // NN, zeroed
    int* cursor    = ibase + 2 * NN;                  // NN, zeroed
    int* hist      = ibase + 3 * NN;                  // 64, zeroed
    int* row_ptr   = ibase + 3 * NN + 64;             // NN+1
    int* col       = ibase + 4 * NN + 65;             // NE
    int* perm      = ibase + 4 * NN + 65 + NE;        // NN
    int* hoff      = perm + NN;                       // 64
    int* bsum      = (int*)hb;                        // NB (scratch)
    int* boffs     = bsum + NB + 8;                   // NB

    const int B = 256;
    const int gather_blocks = (NN * 16 + B - 1) / B;

    // ---- CSR build + norms + degree-sort + packing ----
    (void)hipMemsetAsync(ibase, 0, (3 * NN + 64) * sizeof(int), stream);
    (void)hipMemsetAsync(p, 0, (size_t)NN * D_OUT * sizeof(float), stream);
    degree_kernel<<<(NE + B - 1) / B, B, 0, stream>>>(src, dst, outdeg_i, indeg_i);
    rsqrt_kernel<<<(2 * NN + B - 1) / B, B, 0, stream>>>(outdeg_i, inv_out, 2 * NN);
    bsum_kernel<<<NB, 256, 0, stream>>>(indeg_i, bsum);
    boffs_kernel<<<1, 128, 0, stream>>>(bsum, boffs, row_ptr);
    rowptr_kernel<<<NB, 256, 0, stream>>>(indeg_i, boffs, row_ptr);
    fill_kernel<<<(NE + B - 1) / B, B, 0, stream>>>(src, dst, row_ptr, cursor, col);
    hist_kernel<<<NB, 256, 0, stream>>>(indeg_i, hist);
    hscan_kernel<<<1, 64, 0, stream>>>(hist, hoff);
    permscatter_kernel<<<NB, 256, 0, stream>>>(indeg_i, hoff, perm);
    packw_kernel<<<(368 * 64 + B - 1) / B, B, 0, stream>>>(W0, Wh, Wout, w0p, whp, wop);

    // ---- layer 0 GEMM (fp32 feats -> bf16 frags in-register) ----
    gemm0_kernel<<<G0TILE, 256, 0, stream>>>(feats, w0p, inv_out, tb);

    // ---- fused gather+GEMM layers (degree-balanced blocks) ----
    const ushort_t* tcur = tb;
    ushort_t* tnext = ha;
    for (int l = 0; l < NL; l++) {
        const float* bias_l = (l == 0) ? b0 : bh + (size_t)(l - 1) * D_H;
        fused4_kernel<true, true><<<NTILE, 256, 0, stream>>>(
            tcur, row_ptr, col, perm, inv_in, bias_l,
            whp + (size_t)l * 32 * 512, wop + (size_t)l * 16 * 512,
            inv_out, tnext, p);
        const ushort_t* t = tcur; tcur = tnext; tnext = (ushort_t*)t;
    }
    // tail: h_6 -> p += h_6 @ WoutBlk[6] (no T output)
    fused4_kernel<false, true><<<NTILE, 256, 0, stream>>>(
        tcur, row_ptr, col, perm, inv_in, bh + (size_t)(NL - 1) * D_H,
        nullptr, wop + (size_t)NL * 16 * 512, nullptr, nullptr, p);

    // ---- out = gather(p) + bout (degree-balanced) ----
    gather_f32_kernel<<<gather_blocks, B, 0, stream>>>(p, row_ptr, col, perm, bout, out);
}

// Round 14
// 373.178 us; speedup vs baseline: 1.5083x; 1.5083x over previous
//
#include <hip/hip_runtime.h>

#define NN 30000
#define NE 300000
#define D_IN 256
#define D_H 128
#define D_OUT 64
#define NL 6
#define NB ((NN + 255) / 256)
#define NTILE (NN / 16)          // 1875, exact
#define G0TILE ((NN + 31) / 32)  // 938

typedef unsigned short ushort_t;
typedef unsigned int uint_t;
typedef __attribute__((ext_vector_type(8))) short sh8;
typedef __attribute__((ext_vector_type(4))) float f4;

// fp32 -> bf16 round-to-nearest-even
static __device__ __forceinline__ ushort_t f2bf(float f) {
    uint_t u = __float_as_uint(f);
    u = (u + 0x7FFFu + ((u >> 16) & 1u)) >> 16;
    return (ushort_t)u;
}

// ---------------------------------------------------------------------------
// Setup kernels
// ---------------------------------------------------------------------------
__global__ void degree_kernel(const int* __restrict__ src, const int* __restrict__ dst,
                              int* __restrict__ outdeg, int* __restrict__ indeg) {
    int e = blockIdx.x * blockDim.x + threadIdx.x;
    if (e < NE) {
        atomicAdd(&outdeg[src[e]], 1);
        atomicAdd(&indeg[dst[e]], 1);
    }
}

__global__ void rsqrt_kernel(const int* __restrict__ deg, float* __restrict__ inv, int n) {
    int i = blockIdx.x * blockDim.x + threadIdx.x;
    if (i < n) {
        float d = (float)deg[i];
        inv[i] = rsqrtf(d < 1.0f ? 1.0f : d);
    }
}

__global__ __launch_bounds__(256) void bsum_kernel(const int* __restrict__ deg,
                                                   int* __restrict__ bsum) {
    __shared__ int wsum[4];
    int t = threadIdx.x, lane = t & 63, w = t >> 6;
    int i = blockIdx.x * 256 + t;
    int v = (i < NN) ? deg[i] : 0;
#pragma unroll
    for (int off = 32; off; off >>= 1) v += __shfl_down(v, off, 64);
    if (lane == 0) wsum[w] = v;
    __syncthreads();
    if (t == 0) bsum[blockIdx.x] = wsum[0] + wsum[1] + wsum[2] + wsum[3];
}

__global__ __launch_bounds__(128) void boffs_kernel(const int* __restrict__ bsum,
                                                    int* __restrict__ boffs,
                                                    int* __restrict__ row_ptr) {
    __shared__ int wtot[2];
    int t = threadIdx.x, lane = t & 63, w = t >> 6;
    int v = (t < NB) ? bsum[t] : 0;
    int s = v;
#pragma unroll
    for (int off = 1; off < 64; off <<= 1) {
        int x = __shfl_up(s, off, 64);
        if (lane >= off) s += x;
    }
    if (lane == 63) wtot[w] = s;
    __syncthreads();
    int add = (w == 1) ? wtot[0] : 0;
    if (t < NB) boffs[t] = add + s - v;
    if (t == 0) row_ptr[NN] = NE;
}

__global__ __launch_bounds__(256) void rowptr_kernel(const int* __restrict__ deg,
                                                     const int* __restrict__ boffs,
                                                     int* __restrict__ row_ptr) {
    __shared__ int wsum[4];
    int t = threadIdx.x, lane = t & 63, w = t >> 6;
    int i = blockIdx.x * 256 + t;
    int v = (i < NN) ? deg[i] : 0;
    int s = v;
#pragma unroll
    for (int off = 1; off < 64; off <<= 1) {
        int x = __shfl_up(s, off, 64);
        if (lane >= off) s += x;
    }
    if (lane == 63) wsum[w] = s;
    __syncthreads();
    int woff = 0;
#pragma unroll
    for (int k = 0; k < 4; k++)
        if (k < w) woff += wsum[k];
    if (i < NN) row_ptr[i] = boffs[blockIdx.x] + woff + s - v;
}

__global__ void fill_kernel(const int* __restrict__ src, const int* __restrict__ dst,
                            const int* __restrict__ row_ptr, int* __restrict__ cursor,
                            int* __restrict__ col) {
    int e = blockIdx.x * blockDim.x + threadIdx.x;
    if (e < NE) {
        int d = dst[e];
        int pos = atomicAdd(&cursor[d], 1);
        col[row_ptr[d] + pos] = src[e];
    }
}

// ---------------------------------------------------------------------------
// R14 (= R13 resubmit): degree-balanced perm via CONTENTION-FREE counting
// sort. R12's permscatter (30K device-scope fetch-adds on 64 global
// counters) cost 97 us: ~470 atomics/bucket serialized at ~200ns each.
// Replaced by per-block LDS histograms + one small scan + LDS-cursor
// scatter (~8 us).
// ---------------------------------------------------------------------------
// per-block histogram, bucket-major output bh[bucket*NB + block]
__global__ __launch_bounds__(256) void bhist_kernel(const int* __restrict__ indeg,
                                                    int* __restrict__ bh) {
    __shared__ int h[64];
    int t = threadIdx.x;
    if (t < 64) h[t] = 0;
    __syncthreads();
    int i = blockIdx.x * 256 + t;
    if (i < NN) {
        int b = indeg[i]; if (b > 63) b = 63;
        atomicAdd(&h[b], 1);               // LDS atomic: cheap
    }
    __syncthreads();
    if (t < 64) bh[t * NB + blockIdx.x] = h[t];
}

// in-place exclusive scan of bh[64*NB] (bucket-major), single block.
// 7552 elements = 8 chunks of 1024; verified chunked-scan pattern.
__global__ __launch_bounds__(1024) void gscan_kernel(int* __restrict__ bh) {
    __shared__ int wsum[16];
    __shared__ int chunk_base;
    if (threadIdx.x == 0) chunk_base = 0;
    __syncthreads();
    const int lane = threadIdx.x & 63;
    const int wid = threadIdx.x >> 6;
    const int TOT = 64 * NB;
    for (int base = 0; base < TOT; base += 1024) {
        int i = base + threadIdx.x;
        int v = (i < TOT) ? bh[i] : 0;
        int s = v;
#pragma unroll
        for (int off = 1; off < 64; off <<= 1) {
            int x = __shfl_up(s, off, 64);
            if (lane >= off) s += x;
        }
        if (lane == 63) wsum[wid] = s;
        __syncthreads();
        if (wid == 0 && lane < 16) {
            int ws = wsum[lane];
#pragma unroll
            for (int off = 1; off < 16; off <<= 1) {
                int x = __shfl_up(ws, off, 64);
                if (lane >= off) ws += x;
            }
            wsum[lane] = ws;
        }
        __syncthreads();
        int cb = chunk_base;
        int woff = (wid > 0) ? wsum[wid - 1] : 0;
        int total = wsum[15];
        if (i < TOT) bh[i] = cb + woff + s - v;
        __syncthreads();
        if (threadIdx.x == 0) chunk_base = cb + total;
        __syncthreads();
    }
}

// scatter using per-block LDS cursors seeded from the scanned offsets
__global__ __launch_bounds__(256) void pscatter_kernel(const int* __restrict__ indeg,
                                                       const int* __restrict__ bh,
                                                       int* __restrict__ perm) {
    __shared__ int cur[64];
    int t = threadIdx.x;
    if (t < 64) cur[t] = bh[t * NB + blockIdx.x];
    __syncthreads();
    int i = blockIdx.x * 256 + t;
    if (i < NN) {
        int b = indeg[i]; if (b > 63) b = 63;
        int pos = atomicAdd(&cur[b], 1);   // LDS atomic: cheap
        perm[pos] = i;
    }
}

__global__ void packw_kernel(const float* __restrict__ W0,
                             const float* __restrict__ Wh,
                             const float* __restrict__ Wout,
                             ushort_t* __restrict__ W0p,
                             ushort_t* __restrict__ Whp,
                             ushort_t* __restrict__ Woutp) {
    int g = blockIdx.x * blockDim.x + threadIdx.x;
    int frag = g >> 6;
    int lane = g & 63;
    if (frag >= 368) return;
    const float* srcw;
    ushort_t* dstp;
    int fl, KF, M;
    if (frag < 64) {                     // W0
        fl = frag; KF = 8; M = 128;
        srcw = W0;
        dstp = W0p;
    } else if (frag < 64 + 192) {        // Wh
        int f2 = frag - 64;
        int l = f2 / 32; fl = f2 % 32; KF = 4; M = 128;
        srcw = Wh + (size_t)l * D_H * D_H;
        dstp = Whp + (size_t)l * 32 * 512;
    } else {                             // Wout blocks
        int f2 = frag - 256;
        int l = f2 / 16; fl = f2 % 16; KF = 4; M = 64;
        srcw = Wout + (size_t)l * D_H * D_OUT;
        dstp = Woutp + (size_t)l * 16 * 512;
    }
    int ct = fl / KF;
    int kt = fl % KF;
    int krow = kt * 32 + (lane >> 4) * 8;
    int cidx = ct * 16 + (lane & 15);
    ushort_t tmp[8];
#pragma unroll
    for (int j = 0; j < 8; j++)
        tmp[j] = f2bf(srcw[(size_t)(krow + j) * M + cidx]);
    uint4 o;
    o.x = (uint_t)tmp[0] | ((uint_t)tmp[1] << 16);
    o.y = (uint_t)tmp[2] | ((uint_t)tmp[3] << 16);
    o.z = (uint_t)tmp[4] | ((uint_t)tmp[5] << 16);
    o.w = (uint_t)tmp[6] | ((uint_t)tmp[7] << 16);
    *(uint4*)(dstp + (size_t)fl * 512 + lane * 8) = o;
}

// ---------------------------------------------------------------------------
// Layer-0 GEMM: reads feats fp32 directly, converts to bf16 A-fragments
// in-register. Tb[row,:] = bf16( (feats[row,:] @ W0) * inv_out[row] )
// ---------------------------------------------------------------------------
__global__ __launch_bounds__(256) void gemm0_kernel(
    const float* __restrict__ X,
    const ushort_t* __restrict__ W1p,
    const float* __restrict__ scale,
    ushort_t* __restrict__ Tb)
{
    constexpr int KF = 8;
    const int lane = threadIdx.x & 63;
    const int w = threadIdx.x >> 6;
    const int rg = w >> 1;
    const int cgrp = w & 1;
    const int row0 = blockIdx.x * 32 + rg * 16;

    int arow = row0 + (lane & 15);
    if (arow >= NN) arow = NN - 1;
    const float* xr = X + (size_t)arow * D_IN + ((lane >> 4) * 8);
    sh8 a[KF];
#pragma unroll
    for (int kt = 0; kt < KF; kt++) {
        float4 lo = *(const float4*)(xr + kt * 32);
        float4 hi = *(const float4*)(xr + kt * 32 + 4);
        sh8 t;
        t[0] = (short)f2bf(lo.x); t[1] = (short)f2bf(lo.y);
        t[2] = (short)f2bf(lo.z); t[3] = (short)f2bf(lo.w);
        t[4] = (short)f2bf(hi.x); t[5] = (short)f2bf(hi.y);
        t[6] = (short)f2bf(hi.z); t[7] = (short)f2bf(hi.w);
        a[kt] = t;
    }

    const int crow0 = row0 + (lane >> 4) * 4;
    float s[4];
#pragma unroll
    for (int r = 0; r < 4; r++) {
        int rw = crow0 + r;
        s[r] = scale[rw < NN ? rw : NN - 1];
    }
#pragma unroll
    for (int i = 0; i < 4; i++) {
        int ct = cgrp * 4 + i;
        f4 acc = {0.f, 0.f, 0.f, 0.f};
        const ushort_t* wp = W1p + ((size_t)(ct * KF) << 9) + lane * 8;
#pragma unroll
        for (int kt = 0; kt < KF; kt++)
            acc = __builtin_amdgcn_mfma_f32_16x16x32_bf16(
                a[kt], *(const sh8*)(wp + ((size_t)kt << 9)), acc, 0, 0, 0);
        int colb = ct * 16 + (lane & 15);
#pragma unroll
        for (int r = 0; r < 4; r++) {
            int rw = crow0 + r;
            if (rw < NN)
                Tb[(size_t)rw * 128 + colb] = f2bf(acc[r] * s[r]);
        }
    }
}

// ---------------------------------------------------------------------------
// Fused gather + GEMM, 4 waves per block, 16 degree-matched rows per block
// (rows perm[b*16 .. b*16+16)). Identical compute to R12.
// ---------------------------------------------------------------------------
static __device__ __forceinline__ void acc8(float* acc, uint4 u) {
    uint_t wv[4] = {u.x, u.y, u.z, u.w};
#pragma unroll
    for (int i = 0; i < 4; i++) {
        acc[2 * i]     += __uint_as_float(wv[i] << 16);
        acc[2 * i + 1] += __uint_as_float(wv[i] & 0xFFFF0000u);
    }
}

template <bool HAS_T, bool HAS_P>
__global__ __launch_bounds__(256, 5) void fused4_kernel(
    const ushort_t* __restrict__ Tin,
    const int* __restrict__ row_ptr,
    const int* __restrict__ col,
    const int* __restrict__ perm,
    const float* __restrict__ inv_in,
    const float* __restrict__ bias,      // [128] fp32
    const ushort_t* __restrict__ W1p,    // Wh packed (KF=4), may be null
    const ushort_t* __restrict__ W2p,    // Wout block packed (KF=4)
    const float* __restrict__ inv_out,   // may be null
    ushort_t* __restrict__ Tout,         // may be null
    float* __restrict__ P)
{
    __shared__ float part[4 * 32 * 64];  // [wave][feat(kt*8+i)][lane], 32 KB
    const int tid = threadIdx.x;
    const int lane = tid & 63;
    const int w = tid >> 6;
    const int row0 = blockIdx.x * 16;    // NN % 16 == 0
    const int r = perm[row0 + (lane & 15)];   // degree-matched true node id
    const int beg = row_ptr[r];
    const int end = row_ptr[r + 1];
    const int cb = (lane >> 4) * 8;      // col base (bf16 units)
    const int cq = (lane >> 4) * 4;      // col base (uint units)

    // this wave's contiguous quarter of the row's edge list
    const int cnt = end - beg;
    const int j0 = beg + ((cnt * w) >> 2);
    const int j1 = beg + ((cnt * (w + 1)) >> 2);

    float acc[4][8];
#pragma unroll
    for (int kt = 0; kt < 4; kt++)
#pragma unroll
        for (int i = 0; i < 8; i++) acc[kt][i] = 0.f;

    const uint_t* T32 = (const uint_t*)Tin;   // row = 64 uints
    int j = j0;
    for (; j + 1 < j1; j += 2) {
        int c0 = col[j], c1 = col[j + 1];
        const uint_t* p0 = T32 + (size_t)c0 * 64 + cq;
        const uint_t* p1 = T32 + (size_t)c1 * 64 + cq;
        uint4 u00 = *(const uint4*)(p0);
        uint4 u01 = *(const uint4*)(p0 + 16);
        uint4 u02 = *(const uint4*)(p0 + 32);
        uint4 u03 = *(const uint4*)(p0 + 48);
        uint4 u10 = *(const uint4*)(p1);
        uint4 u11 = *(const uint4*)(p1 + 16);
        uint4 u12 = *(const uint4*)(p1 + 32);
        uint4 u13 = *(const uint4*)(p1 + 48);
        acc8(acc[0], u00); acc8(acc[0], u10);
        acc8(acc[1], u01); acc8(acc[1], u11);
        acc8(acc[2], u02); acc8(acc[2], u12);
        acc8(acc[3], u03); acc8(acc[3], u13);
    }
    if (j < j1) {
        int c0 = col[j];
        const uint_t* p0 = T32 + (size_t)c0 * 64 + cq;
        acc8(acc[0], *(const uint4*)(p0));
        acc8(acc[1], *(const uint4*)(p0 + 16));
        acc8(acc[2], *(const uint4*)(p0 + 32));
        acc8(acc[3], *(const uint4*)(p0 + 48));
    }

    // publish partials: [w][kt*8+i][lane] -> bank = lane%32, conflict-free
#pragma unroll
    for (int kt = 0; kt < 4; kt++)
#pragma unroll
        for (int i = 0; i < 8; i++)
            part[(w * 32 + kt * 8 + i) * 64 + lane] = acc[kt][i];
    __syncthreads();

    // each wave completes the sum for its own lane slot (adds 3 other waves)
#pragma unroll
    for (int ow = 1; ow < 4; ow++) {
        int w2 = (w + ow) & 3;
#pragma unroll
        for (int kt = 0; kt < 4; kt++)
#pragma unroll
            for (int i = 0; i < 8; i++)
                acc[kt][i] += part[(w2 * 32 + kt * 8 + i) * 64 + lane];
    }

    // finish: bias + relu + inv_in scale, convert to A-fragments
    const float s = inv_in[r];
    sh8 a[4];
#pragma unroll
    for (int kt = 0; kt < 4; kt++) {
        float4 b0 = *(const float4*)(bias + kt * 32 + cb);
        float4 b1 = *(const float4*)(bias + kt * 32 + cb + 4);
        float bb[8] = {b0.x, b0.y, b0.z, b0.w, b1.x, b1.y, b1.z, b1.w};
        sh8 t;
#pragma unroll
        for (int i = 0; i < 8; i++) {
            float h = fmaxf(fmaf(acc[kt][i], s, bb[i]), 0.f);
            t[i] = (short)f2bf(h);
        }
        a[kt] = t;
    }

    // output rows for the MFMA C-tile (perm'd true node ids)
    const int crow0 = row0 + (lane >> 4) * 4;
    int prow[4];
#pragma unroll
    for (int rr = 0; rr < 4; rr++)
        prow[rr] = perm[crow0 + rr];

    if (HAS_T) {
        // 12 units (T ct 0..7, P ct 0..3), 3 per wave
        float sc[4];
#pragma unroll
        for (int rr = 0; rr < 4; rr++)
            sc[rr] = inv_out[prow[rr]];
#pragma unroll
        for (int u = 0; u < 3; u++) {
            int unit = w * 3 + u;
            if (unit < 8) {
                int ct = unit;
                f4 accT = {0.f, 0.f, 0.f, 0.f};
                const ushort_t* wp = W1p + ((size_t)(ct * 4) << 9) + lane * 8;
#pragma unroll
                for (int kt = 0; kt < 4; kt++)
                    accT = __builtin_amdgcn_mfma_f32_16x16x32_bf16(
                        a[kt], *(const sh8*)(wp + ((size_t)kt << 9)), accT, 0, 0, 0);
                int colb = ct * 16 + (lane & 15);
#pragma unroll
                for (int rr = 0; rr < 4; rr++)
                    Tout[(size_t)prow[rr] * 128 + colb] = f2bf(accT[rr] * sc[rr]);
            } else {
                int ct = unit - 8;
                f4 accP = {0.f, 0.f, 0.f, 0.f};
                const ushort_t* wp = W2p + ((size_t)(ct * 4) << 9) + lane * 8;
#pragma unroll
                for (int kt = 0; kt < 4; kt++)
                    accP = __builtin_amdgcn_mfma_f32_16x16x32_bf16(
                        a[kt], *(const sh8*)(wp + ((size_t)kt << 9)), accP, 0, 0, 0);
                int colb = ct * 16 + (lane & 15);
#pragma unroll
                for (int rr = 0; rr < 4; rr++)
                    P[(size_t)prow[rr] * 64 + colb] += accP[rr];
            }
        }
    } else if (HAS_P) {
        // tail: 4 P units, 1 per wave
        int ct = w;
        f4 accP = {0.f, 0.f, 0.f, 0.f};
        const ushort_t* wp = W2p + ((size_t)(ct * 4) << 9) + lane * 8;
#pragma unroll
        for (int kt = 0; kt < 4; kt++)
            accP = __builtin_amdgcn_mfma_f32_16x16x32_bf16(
                a[kt], *(const sh8*)(wp + ((size_t)kt << 9)), accP, 0, 0, 0);
        int colb = ct * 16 + (lane & 15);
#pragma unroll
        for (int rr = 0; rr < 4; rr++)
            P[(size_t)prow[rr] * 64 + colb] += accP[rr];
    }
}

// fp32 final gather, degree-balanced: out[perm[slot],:] = sum p[col[j],:] + bout
__global__ __launch_bounds__(256) void gather_f32_kernel(
    const float* __restrict__ P,
    const int* __restrict__ row_ptr,
    const int* __restrict__ col,
    const int* __restrict__ perm,
    const float* __restrict__ bias,
    float* __restrict__ Y) {
    int idx = blockIdx.x * blockDim.x + threadIdx.x;
    int slot = idx >> 4;
    int q = idx & 15;
    if (slot >= NN) return;
    int node = perm[slot];
    int beg = row_ptr[node];
    int end = row_ptr[node + 1];
    float4 acc = make_float4(0.f, 0.f, 0.f, 0.f);
    int j = beg;
    for (; j + 3 < end; j += 4) {
        int c0 = col[j], c1 = col[j + 1], c2 = col[j + 2], c3 = col[j + 3];
        float4 v0 = *(const float4*)(P + (size_t)c0 * 64 + q * 4);
        float4 v1 = *(const float4*)(P + (size_t)c1 * 64 + q * 4);
        float4 v2 = *(const float4*)(P + (size_t)c2 * 64 + q * 4);
        float4 v3 = *(const float4*)(P + (size_t)c3 * 64 + q * 4);
        acc.x += (v0.x + v1.x) + (v2.x + v3.x);
        acc.y += (v0.y + v1.y) + (v2.y + v3.y);
        acc.z += (v0.z + v1.z) + (v2.z + v3.z);
        acc.w += (v0.w + v1.w) + (v2.w + v3.w);
    }
    for (; j < end; j++) {
        int c0 = col[j];
        float4 v0 = *(const float4*)(P + (size_t)c0 * 64 + q * 4);
        acc.x += v0.x; acc.y += v0.y; acc.z += v0.z; acc.w += v0.w;
    }
    float4 b = *(const float4*)(bias + q * 4);
    acc.x += b.x; acc.y += b.y; acc.z += b.z; acc.w += b.w;
    *(float4*)(Y + (size_t)node * 64 + q * 4) = acc;
}

// ---------------------------------------------------------------------------
extern "C" void kernel_launch(void* const* d_in, const int* in_sizes, int n_in,
                              void* d_out, int out_size, void* d_ws, size_t ws_size,
                              hipStream_t stream) {
    const float* feats = (const float*)d_in[0];
    const int*   src   = (const int*)d_in[1];
    const int*   dst   = (const int*)d_in[2];
    const float* W0    = (const float*)d_in[3];
    const float* b0    = (const float*)d_in[4];
    const float* Wh    = (const float*)d_in[5];
    const float* bh_   = (const float*)d_in[6];
    const float* Wout  = (const float*)d_in[7];
    const float* bout  = (const float*)d_in[8];
    float* out = (float*)d_out;

    float* ws      = (float*)d_ws;
    float* inv_out = ws;                              // NN
    float* inv_in  = ws + NN;                         // NN
    float* p       = ws + 2 * NN;                     // NN*64 fp32
    ushort_t* tb   = (ushort_t*)(p + (size_t)NN * 64);      // NN*128 bf16
    ushort_t* ha   = tb + (size_t)NN * 128;           // NN*128 bf16
    ushort_t* hb   = ha + (size_t)NN * 128;           // NN*128 bf16 (scan scratch)
    ushort_t* fb   = hb + (size_t)NN * 128;           // NN*256 bf16 (unused)
    ushort_t* w0p  = fb + (size_t)NN * 256;           // 64*512
    ushort_t* whp  = w0p + 64 * 512;                  // 192*512
    ushort_t* wop  = whp + 192 * 512;                 // 112*512
    int* ibase     = (int*)(wop + 112 * 512);
    int* outdeg_i  = ibase;                           // NN, zeroed
    int* indeg_i   = ibase + NN;                      // NN, zeroed
    int* cursor    = ibase + 2 * NN;                  // NN, zeroed
    int* row_ptr   = ibase + 3 * NN;                  // NN+1
    int* col       = ibase + 4 * NN + 1;              // NE
    int* perm      = ibase + 4 * NN + 1 + NE;         // NN
    int* bsum      = (int*)hb;                        // NB (scratch)
    int* boffs     = bsum + NB + 8;                   // NB
    int* bhtab     = boffs + NB + 8;                  // 64*NB (scratch)

    const int B = 256;
    const int gather_blocks = (NN * 16 + B - 1) / B;

    // ---- CSR build + norms + degree-sort + packing ----
    (void)hipMemsetAsync(ibase, 0, 3 * NN * sizeof(int), stream);
    (void)hipMemsetAsync(p, 0, (size_t)NN * D_OUT * sizeof(float), stream);
    degree_kernel<<<(NE + B - 1) / B, B, 0, stream>>>(src, dst, outdeg_i, indeg_i);
    rsqrt_kernel<<<(2 * NN + B - 1) / B, B, 0, stream>>>(outdeg_i, inv_out, 2 * NN);
    bsum_kernel<<<NB, 256, 0, stream>>>(indeg_i, bsum);
    boffs_kernel<<<1, 128, 0, stream>>>(bsum, boffs, row_ptr);
    rowptr_kernel<<<NB, 256, 0, stream>>>(indeg_i, boffs, row_ptr);
    fill_kernel<<<(NE + B - 1) / B, B, 0, stream>>>(src, dst, row_ptr, cursor, col);
    bhist_kernel<<<NB, 256, 0, stream>>>(indeg_i, bhtab);
    gscan_kernel<<<1, 1024, 0, stream>>>(bhtab);
    pscatter_kernel<<<NB, 256, 0, stream>>>(indeg_i, bhtab, perm);
    packw_kernel<<<(368 * 64 + B - 1) / B, B, 0, stream>>>(W0, Wh, Wout, w0p, whp, wop);

    // ---- layer 0 GEMM (fp32 feats -> bf16 frags in-register) ----
    gemm0_kernel<<<G0TILE, 256, 0, stream>>>(feats, w0p, inv_out, tb);

    // ---- fused gather+GEMM layers (degree-balanced blocks) ----
    const ushort_t* tcur = tb;
    ushort_t* tnext = ha;
    for (int l = 0; l < NL; l++) {
        const float* bias_l = (l == 0) ? b0 : bh_ + (size_t)(l - 1) * D_H;
        fused4_kernel<true, true><<<NTILE, 256, 0, stream>>>(
            tcur, row_ptr, col, perm, inv_in, bias_l,
            whp + (size_t)l * 32 * 512, wop + (size_t)l * 16 * 512,
            inv_out, tnext, p);
        const ushort_t* t = tcur; tcur = tnext; tnext = (ushort_t*)t;
    }
    // tail: h_6 -> p += h_6 @ WoutBlk[6] (no T output)
    fused4_kernel<false, true><<<NTILE, 256, 0, stream>>>(
        tcur, row_ptr, col, perm, inv_in, bh_ + (size_t)(NL - 1) * D_H,
        nullptr, wop + (size_t)NL * 16 * 512, nullptr, nullptr, p);

    // ---- out = gather(p) + bout (degree-balanced) ----
    gather_f32_kernel<<<gather_blocks, B, 0, stream>>>(p, row_ptr, col, perm, bout, out);
}

// Round 15
// 326.606 us; speedup vs baseline: 1.7234x; 1.1426x over previous
//
#include <hip/hip_runtime.h>

#define NN 30000
#define NE 300000
#define D_IN 256
#define D_H 128
#define D_OUT 64
#define NL 6
#define NB ((NN + 255) / 256)
#define NTILE (NN / 16)          // 1875, exact
#define G0TILE ((NN + 31) / 32)  // 938

typedef unsigned short ushort_t;
typedef unsigned int uint_t;
typedef __attribute__((ext_vector_type(8))) short sh8;
typedef __attribute__((ext_vector_type(4))) float f4;

// fp32 -> bf16 round-to-nearest-even
static __device__ __forceinline__ ushort_t f2bf(float f) {
    uint_t u = __float_as_uint(f);
    u = (u + 0x7FFFu + ((u >> 16) & 1u)) >> 16;
    return (ushort_t)u;
}

// ---------------------------------------------------------------------------
// Setup kernels
// ---------------------------------------------------------------------------
__global__ void degree_kernel(const int* __restrict__ src, const int* __restrict__ dst,
                              int* __restrict__ outdeg, int* __restrict__ indeg) {
    int e = blockIdx.x * blockDim.x + threadIdx.x;
    if (e < NE) {
        atomicAdd(&outdeg[src[e]], 1);
        atomicAdd(&indeg[dst[e]], 1);
    }
}

__global__ void rsqrt_kernel(const int* __restrict__ deg, float* __restrict__ inv, int n) {
    int i = blockIdx.x * blockDim.x + threadIdx.x;
    if (i < n) {
        float d = (float)deg[i];
        inv[i] = rsqrtf(d < 1.0f ? 1.0f : d);
    }
}

__global__ __launch_bounds__(256) void bsum_kernel(const int* __restrict__ deg,
                                                   int* __restrict__ bsum) {
    __shared__ int wsum[4];
    int t = threadIdx.x, lane = t & 63, w = t >> 6;
    int i = blockIdx.x * 256 + t;
    int v = (i < NN) ? deg[i] : 0;
#pragma unroll
    for (int off = 32; off; off >>= 1) v += __shfl_down(v, off, 64);
    if (lane == 0) wsum[w] = v;
    __syncthreads();
    if (t == 0) bsum[blockIdx.x] = wsum[0] + wsum[1] + wsum[2] + wsum[3];
}

__global__ __launch_bounds__(128) void boffs_kernel(const int* __restrict__ bsum,
                                                    int* __restrict__ boffs,
                                                    int* __restrict__ row_ptr) {
    __shared__ int wtot[2];
    int t = threadIdx.x, lane = t & 63, w = t >> 6;
    int v = (t < NB) ? bsum[t] : 0;
    int s = v;
#pragma unroll
    for (int off = 1; off < 64; off <<= 1) {
        int x = __shfl_up(s, off, 64);
        if (lane >= off) s += x;
    }
    if (lane == 63) wtot[w] = s;
    __syncthreads();
    int add = (w == 1) ? wtot[0] : 0;
    if (t < NB) boffs[t] = add + s - v;
    if (t == 0) row_ptr[NN] = NE;
}

__global__ __launch_bounds__(256) void rowptr_kernel(const int* __restrict__ deg,
                                                     const int* __restrict__ boffs,
                                                     int* __restrict__ row_ptr) {
    __shared__ int wsum[4];
    int t = threadIdx.x, lane = t & 63, w = t >> 6;
    int i = blockIdx.x * 256 + t;
    int v = (i < NN) ? deg[i] : 0;
    int s = v;
#pragma unroll
    for (int off = 1; off < 64; off <<= 1) {
        int x = __shfl_up(s, off, 64);
        if (lane >= off) s += x;
    }
    if (lane == 63) wsum[w] = s;
    __syncthreads();
    int woff = 0;
#pragma unroll
    for (int k = 0; k < 4; k++)
        if (k < w) woff += wsum[k];
    if (i < NN) row_ptr[i] = boffs[blockIdx.x] + woff + s - v;
}

__global__ void fill_kernel(const int* __restrict__ src, const int* __restrict__ dst,
                            const int* __restrict__ row_ptr, int* __restrict__ cursor,
                            int* __restrict__ col) {
    int e = blockIdx.x * blockDim.x + threadIdx.x;
    if (e < NE) {
        int d = dst[e];
        int pos = atomicAdd(&cursor[d], 1);
        col[row_ptr[d] + pos] = src[e];
    }
}

__global__ void packw_kernel(const float* __restrict__ W0,
                             const float* __restrict__ Wh,
                             const float* __restrict__ Wout,
                             ushort_t* __restrict__ W0p,
                             ushort_t* __restrict__ Whp,
                             ushort_t* __restrict__ Woutp) {
    int g = blockIdx.x * blockDim.x + threadIdx.x;
    int frag = g >> 6;
    int lane = g & 63;
    if (frag >= 368) return;
    const float* srcw;
    ushort_t* dstp;
    int fl, KF, M;
    if (frag < 64) {                     // W0
        fl = frag; KF = 8; M = 128;
        srcw = W0;
        dstp = W0p;
    } else if (frag < 64 + 192) {        // Wh
        int f2 = frag - 64;
        int l = f2 / 32; fl = f2 % 32; KF = 4; M = 128;
        srcw = Wh + (size_t)l * D_H * D_H;
        dstp = Whp + (size_t)l * 32 * 512;
    } else {                             // Wout blocks
        int f2 = frag - 256;
        int l = f2 / 16; fl = f2 % 16; KF = 4; M = 64;
        srcw = Wout + (size_t)l * D_H * D_OUT;
        dstp = Woutp + (size_t)l * 16 * 512;
    }
    int ct = fl / KF;
    int kt = fl % KF;
    int krow = kt * 32 + (lane >> 4) * 8;
    int cidx = ct * 16 + (lane & 15);
    ushort_t tmp[8];
#pragma unroll
    for (int j = 0; j < 8; j++)
        tmp[j] = f2bf(srcw[(size_t)(krow + j) * M + cidx]);
    uint4 o;
    o.x = (uint_t)tmp[0] | ((uint_t)tmp[1] << 16);
    o.y = (uint_t)tmp[2] | ((uint_t)tmp[3] << 16);
    o.z = (uint_t)tmp[4] | ((uint_t)tmp[5] << 16);
    o.w = (uint_t)tmp[6] | ((uint_t)tmp[7] << 16);
    *(uint4*)(dstp + (size_t)fl * 512 + lane * 8) = o;
}

// ---------------------------------------------------------------------------
// Layer-0 GEMM: reads feats fp32 directly, converts to bf16 A-fragments
// in-register. Tb[row,:] = bf16( (feats[row,:] @ W0) * inv_out[row] )
// ---------------------------------------------------------------------------
__global__ __launch_bounds__(256) void gemm0_kernel(
    const float* __restrict__ X,
    const ushort_t* __restrict__ W1p,
    const float* __restrict__ scale,
    ushort_t* __restrict__ Tb)
{
    constexpr int KF = 8;
    const int lane = threadIdx.x & 63;
    const int w = threadIdx.x >> 6;
    const int rg = w >> 1;
    const int cgrp = w & 1;
    const int row0 = blockIdx.x * 32 + rg * 16;

    int arow = row0 + (lane & 15);
    if (arow >= NN) arow = NN - 1;
    const float* xr = X + (size_t)arow * D_IN + ((lane >> 4) * 8);
    sh8 a[KF];
#pragma unroll
    for (int kt = 0; kt < KF; kt++) {
        float4 lo = *(const float4*)(xr + kt * 32);
        float4 hi = *(const float4*)(xr + kt * 32 + 4);
        sh8 t;
        t[0] = (short)f2bf(lo.x); t[1] = (short)f2bf(lo.y);
        t[2] = (short)f2bf(lo.z); t[3] = (short)f2bf(lo.w);
        t[4] = (short)f2bf(hi.x); t[5] = (short)f2bf(hi.y);
        t[6] = (short)f2bf(hi.z); t[7] = (short)f2bf(hi.w);
        a[kt] = t;
    }

    const int crow0 = row0 + (lane >> 4) * 4;
    float s[4];
#pragma unroll
    for (int r = 0; r < 4; r++) {
        int rw = crow0 + r;
        s[r] = scale[rw < NN ? rw : NN - 1];
    }
#pragma unroll
    for (int i = 0; i < 4; i++) {
        int ct = cgrp * 4 + i;
        f4 acc = {0.f, 0.f, 0.f, 0.f};
        const ushort_t* wp = W1p + ((size_t)(ct * KF) << 9) + lane * 8;
#pragma unroll
        for (int kt = 0; kt < KF; kt++)
            acc = __builtin_amdgcn_mfma_f32_16x16x32_bf16(
                a[kt], *(const sh8*)(wp + ((size_t)kt << 9)), acc, 0, 0, 0);
        int colb = ct * 16 + (lane & 15);
#pragma unroll
        for (int r = 0; r < 4; r++) {
            int rw = crow0 + r;
            if (rw < NN)
                Tb[(size_t)rw * 128 + colb] = f2bf(acc[r] * s[r]);
        }
    }
}

// ---------------------------------------------------------------------------
// Fused gather + GEMM, 4 waves per block, 16 rows per block.
// __launch_bounds__(256, 5): 5 blocks/CU (5 x 32 KB LDS = 160 KB), 20
// waves/CU. Measured best: 327.6 us (R10). Degree-balanced perm (R14)
// regressed to 373 us: the L2-locality loss of scattered col-ranges and
// scattered T/P writes exceeds the ~1.2x divergence saving.
// ---------------------------------------------------------------------------
static __device__ __forceinline__ void acc8(float* acc, uint4 u) {
    uint_t wv[4] = {u.x, u.y, u.z, u.w};
#pragma unroll
    for (int i = 0; i < 4; i++) {
        acc[2 * i]     += __uint_as_float(wv[i] << 16);
        acc[2 * i + 1] += __uint_as_float(wv[i] & 0xFFFF0000u);
    }
}

template <bool HAS_T, bool HAS_P>
__global__ __launch_bounds__(256, 5) void fused4_kernel(
    const ushort_t* __restrict__ Tin,
    const int* __restrict__ row_ptr,
    const int* __restrict__ col,
    const float* __restrict__ inv_in,
    const float* __restrict__ bias,      // [128] fp32
    const ushort_t* __restrict__ W1p,    // Wh packed (KF=4), may be null
    const ushort_t* __restrict__ W2p,    // Wout block packed (KF=4)
    const float* __restrict__ inv_out,   // may be null
    ushort_t* __restrict__ Tout,         // may be null
    float* __restrict__ P)
{
    __shared__ float part[4 * 32 * 64];  // [wave][feat(kt*8+i)][lane], 32 KB
    const int tid = threadIdx.x;
    const int lane = tid & 63;
    const int w = tid >> 6;
    const int row0 = blockIdx.x * 16;    // NN % 16 == 0
    const int r = row0 + (lane & 15);
    const int beg = row_ptr[r];
    const int end = row_ptr[r + 1];
    const int cb = (lane >> 4) * 8;      // col base (bf16 units)
    const int cq = (lane >> 4) * 4;      // col base (uint units)

    // this wave's contiguous quarter of the row's edge list
    const int cnt = end - beg;
    const int j0 = beg + ((cnt * w) >> 2);
    const int j1 = beg + ((cnt * (w + 1)) >> 2);

    float acc[4][8];
#pragma unroll
    for (int kt = 0; kt < 4; kt++)
#pragma unroll
        for (int i = 0; i < 8; i++) acc[kt][i] = 0.f;

    const uint_t* T32 = (const uint_t*)Tin;   // row = 64 uints
    int j = j0;
    for (; j + 1 < j1; j += 2) {
        int c0 = col[j], c1 = col[j + 1];
        const uint_t* p0 = T32 + (size_t)c0 * 64 + cq;
        const uint_t* p1 = T32 + (size_t)c1 * 64 + cq;
        uint4 u00 = *(const uint4*)(p0);
        uint4 u01 = *(const uint4*)(p0 + 16);
        uint4 u02 = *(const uint4*)(p0 + 32);
        uint4 u03 = *(const uint4*)(p0 + 48);
        uint4 u10 = *(const uint4*)(p1);
        uint4 u11 = *(const uint4*)(p1 + 16);
        uint4 u12 = *(const uint4*)(p1 + 32);
        uint4 u13 = *(const uint4*)(p1 + 48);
        acc8(acc[0], u00); acc8(acc[0], u10);
        acc8(acc[1], u01); acc8(acc[1], u11);
        acc8(acc[2], u02); acc8(acc[2], u12);
        acc8(acc[3], u03); acc8(acc[3], u13);
    }
    if (j < j1) {
        int c0 = col[j];
        const uint_t* p0 = T32 + (size_t)c0 * 64 + cq;
        acc8(acc[0], *(const uint4*)(p0));
        acc8(acc[1], *(const uint4*)(p0 + 16));
        acc8(acc[2], *(const uint4*)(p0 + 32));
        acc8(acc[3], *(const uint4*)(p0 + 48));
    }

    // publish partials: [w][kt*8+i][lane] -> bank = lane%32, conflict-free
#pragma unroll
    for (int kt = 0; kt < 4; kt++)
#pragma unroll
        for (int i = 0; i < 8; i++)
            part[(w * 32 + kt * 8 + i) * 64 + lane] = acc[kt][i];
    __syncthreads();

    // each wave completes the sum for its own lane slot (adds 3 other waves)
#pragma unroll
    for (int ow = 1; ow < 4; ow++) {
        int w2 = (w + ow) & 3;
#pragma unroll
        for (int kt = 0; kt < 4; kt++)
#pragma unroll
            for (int i = 0; i < 8; i++)
                acc[kt][i] += part[(w2 * 32 + kt * 8 + i) * 64 + lane];
    }

    // finish: bias + relu + inv_in scale, convert to A-fragments
    const float s = inv_in[r];
    sh8 a[4];
#pragma unroll
    for (int kt = 0; kt < 4; kt++) {
        float4 b0 = *(const float4*)(bias + kt * 32 + cb);
        float4 b1 = *(const float4*)(bias + kt * 32 + cb + 4);
        float bb[8] = {b0.x, b0.y, b0.z, b0.w, b1.x, b1.y, b1.z, b1.w};
        sh8 t;
#pragma unroll
        for (int i = 0; i < 8; i++) {
            float h = fmaxf(fmaf(acc[kt][i], s, bb[i]), 0.f);
            t[i] = (short)f2bf(h);
        }
        a[kt] = t;
    }

    const int crow0 = row0 + (lane >> 4) * 4;

    if (HAS_T) {
        // 12 units (T ct 0..7, P ct 0..3), 3 per wave
        float sc[4];
#pragma unroll
        for (int rr = 0; rr < 4; rr++)
            sc[rr] = inv_out[crow0 + rr];
#pragma unroll
        for (int u = 0; u < 3; u++) {
            int unit = w * 3 + u;
            if (unit < 8) {
                int ct = unit;
                f4 accT = {0.f, 0.f, 0.f, 0.f};
                const ushort_t* wp = W1p + ((size_t)(ct * 4) << 9) + lane * 8;
#pragma unroll
                for (int kt = 0; kt < 4; kt++)
                    accT = __builtin_amdgcn_mfma_f32_16x16x32_bf16(
                        a[kt], *(const sh8*)(wp + ((size_t)kt << 9)), accT, 0, 0, 0);
                int colb = ct * 16 + (lane & 15);
#pragma unroll
                for (int rr = 0; rr < 4; rr++)
                    Tout[(size_t)(crow0 + rr) * 128 + colb] = f2bf(accT[rr] * sc[rr]);
            } else {
                int ct = unit - 8;
                f4 accP = {0.f, 0.f, 0.f, 0.f};
                const ushort_t* wp = W2p + ((size_t)(ct * 4) << 9) + lane * 8;
#pragma unroll
                for (int kt = 0; kt < 4; kt++)
                    accP = __builtin_amdgcn_mfma_f32_16x16x32_bf16(
                        a[kt], *(const sh8*)(wp + ((size_t)kt << 9)), accP, 0, 0, 0);
                int colb = ct * 16 + (lane & 15);
#pragma unroll
                for (int rr = 0; rr < 4; rr++)
                    P[(size_t)(crow0 + rr) * 64 + colb] += accP[rr];
            }
        }
    } else if (HAS_P) {
        // tail: 4 P units, 1 per wave
        int ct = w;
        f4 accP = {0.f, 0.f, 0.f, 0.f};
        const ushort_t* wp = W2p + ((size_t)(ct * 4) << 9) + lane * 8;
#pragma unroll
        for (int kt = 0; kt < 4; kt++)
            accP = __builtin_amdgcn_mfma_f32_16x16x32_bf16(
                a[kt], *(const sh8*)(wp + ((size_t)kt << 9)), accP, 0, 0, 0);
        int colb = ct * 16 + (lane & 15);
#pragma unroll
        for (int rr = 0; rr < 4; rr++)
            P[(size_t)(crow0 + rr) * 64 + colb] += accP[rr];
    }
}

// fp32 final gather, 4x-unrolled: out[node,0:64] = sum p[col[j],:] + bout
__global__ __launch_bounds__(256) void gather_f32_kernel(
    const float* __restrict__ P,
    const int* __restrict__ row_ptr,
    const int* __restrict__ col,
    const float* __restrict__ bias,
    float* __restrict__ Y) {
    int idx = blockIdx.x * blockDim.x + threadIdx.x;
    int node = idx >> 4;
    int q = idx & 15;
    if (node >= NN) return;
    int beg = row_ptr[node];
    int end = row_ptr[node + 1];
    float4 acc = make_float4(0.f, 0.f, 0.f, 0.f);
    int j = beg;
    for (; j + 3 < end; j += 4) {
        int c0 = col[j], c1 = col[j + 1], c2 = col[j + 2], c3 = col[j + 3];
        float4 v0 = *(const float4*)(P + (size_t)c0 * 64 + q * 4);
        float4 v1 = *(const float4*)(P + (size_t)c1 * 64 + q * 4);
        float4 v2 = *(const float4*)(P + (size_t)c2 * 64 + q * 4);
        float4 v3 = *(const float4*)(P + (size_t)c3 * 64 + q * 4);
        acc.x += (v0.x + v1.x) + (v2.x + v3.x);
        acc.y += (v0.y + v1.y) + (v2.y + v3.y);
        acc.z += (v0.z + v1.z) + (v2.z + v3.z);
        acc.w += (v0.w + v1.w) + (v2.w + v3.w);
    }
    for (; j < end; j++) {
        int c0 = col[j];
        float4 v0 = *(const float4*)(P + (size_t)c0 * 64 + q * 4);
        acc.x += v0.x; acc.y += v0.y; acc.z += v0.z; acc.w += v0.w;
    }
    float4 b = *(const float4*)(bias + q * 4);
    acc.x += b.x; acc.y += b.y; acc.z += b.z; acc.w += b.w;
    *(float4*)(Y + (size_t)node * 64 + q * 4) = acc;
}

// ---------------------------------------------------------------------------
extern "C" void kernel_launch(void* const* d_in, const int* in_sizes, int n_in,
                              void* d_out, int out_size, void* d_ws, size_t ws_size,
                              hipStream_t stream) {
    const float* feats = (const float*)d_in[0];
    const int*   src   = (const int*)d_in[1];
    const int*   dst   = (const int*)d_in[2];
    const float* W0    = (const float*)d_in[3];
    const float* b0    = (const float*)d_in[4];
    const float* Wh    = (const float*)d_in[5];
    const float* bh    = (const float*)d_in[6];
    const float* Wout  = (const float*)d_in[7];
    const float* bout  = (const float*)d_in[8];
    float* out = (float*)d_out;

    float* ws      = (float*)d_ws;
    float* inv_out = ws;                              // NN
    float* inv_in  = ws + NN;                         // NN
    float* p       = ws + 2 * NN;                     // NN*64 fp32
    ushort_t* tb   = (ushort_t*)(p + (size_t)NN * 64);      // NN*128 bf16
    ushort_t* ha   = tb + (size_t)NN * 128;           // NN*128 bf16
    ushort_t* hb   = ha + (size_t)NN * 128;           // NN*128 bf16 (scan scratch)
    ushort_t* fb   = hb + (size_t)NN * 128;           // NN*256 bf16 (unused)
    ushort_t* w0p  = fb + (size_t)NN * 256;           // 64*512
    ushort_t* whp  = w0p + 64 * 512;                  // 192*512
    ushort_t* wop  = whp + 192 * 512;                 // 112*512
    int* ibase     = (int*)(wop + 112 * 512);
    int* outdeg_i  = ibase;                           // NN (zeroed together)
    int* indeg_i   = ibase + NN;                      // NN (zeroed together)
    int* cursor    = ibase + 2 * NN;                  // NN (zeroed together)
    int* row_ptr   = ibase + 3 * NN;                  // NN+1
    int* col       = ibase + 4 * NN + 1;              // NE
    int* bsum      = (int*)hb;                        // NB (scratch)
    int* boffs     = bsum + NB + 8;                   // NB

    const int B = 256;
    const int gather_blocks = (NN * 16 + B - 1) / B;

    // ---- CSR build + norms + packing ----
    (void)hipMemsetAsync(ibase, 0, 3 * NN * sizeof(int), stream);
    (void)hipMemsetAsync(p, 0, (size_t)NN * D_OUT * sizeof(float), stream);
    degree_kernel<<<(NE + B - 1) / B, B, 0, stream>>>(src, dst, outdeg_i, indeg_i);
    rsqrt_kernel<<<(2 * NN + B - 1) / B, B, 0, stream>>>(outdeg_i, inv_out, 2 * NN);
    bsum_kernel<<<NB, 256, 0, stream>>>(indeg_i, bsum);
    boffs_kernel<<<1, 128, 0, stream>>>(bsum, boffs, row_ptr);
    rowptr_kernel<<<NB, 256, 0, stream>>>(indeg_i, boffs, row_ptr);
    fill_kernel<<<(NE + B - 1) / B, B, 0, stream>>>(src, dst, row_ptr, cursor, col);
    packw_kernel<<<(368 * 64 + B - 1) / B, B, 0, stream>>>(W0, Wh, Wout, w0p, whp, wop);

    // ---- layer 0 GEMM (fp32 feats -> bf16 frags in-register) ----
    gemm0_kernel<<<G0TILE, 256, 0, stream>>>(feats, w0p, inv_out, tb);

    // ---- fused gather+GEMM layers (4-wave blocks, 5 blocks/CU) ----
    const ushort_t* tcur = tb;
    ushort_t* tnext = ha;
    for (int l = 0; l < NL; l++) {
        const float* bias_l = (l == 0) ? b0 : bh + (size_t)(l - 1) * D_H;
        fused4_kernel<true, true><<<NTILE, 256, 0, stream>>>(
            tcur, row_ptr, col, inv_in, bias_l,
            whp + (size_t)l * 32 * 512, wop + (size_t)l * 16 * 512,
            inv_out, tnext, p);
        const ushort_t* t = tcur; tcur = tnext; tnext = (ushort_t*)t;
    }
    // tail: h_6 -> p += h_6 @ WoutBlk[6] (no T output)
    fused4_kernel<false, true><<<NTILE, 256, 0, stream>>>(
        tcur, row_ptr, col, inv_in, bh + (size_t)(NL - 1) * D_H,
        nullptr, wop + (size_t)NL * 16 * 512, nullptr, nullptr, p);

    // ---- out = gather(p) + bout ----
    gather_f32_kernel<<<gather_blocks, B, 0, stream>>>(p, row_ptr, col, bout, out);
}